// Round 5
// baseline (323.404 us; speedup 1.0000x reference)
//
#include <hip/hip_runtime.h>

typedef unsigned short u16;
typedef _Float16 f16x8 __attribute__((ext_vector_type(8)));
typedef float f32x4 __attribute__((ext_vector_type(4)));

__device__ __forceinline__ u16 f2h(float f){
  _Float16 h = (_Float16)f; u16 u; __builtin_memcpy(&u, &h, 2); return u;
}
__device__ __forceinline__ float h2f(u16 u){
  _Float16 h; __builtin_memcpy(&h, &u, 2); return (float)h;
}
__device__ __forceinline__ unsigned pk2h(float a, float b){
  auto r = __builtin_amdgcn_cvt_pkrtz(a, b);   // __fp16 ext_vector_type(2)
  unsigned u; __builtin_memcpy(&u, &r, 4); return u;
}
__device__ __forceinline__ float sigm(float x){ return 1.0f/(1.0f + __expf(-x)); }
__device__ __forceinline__ f32x4 zero4(){ f32x4 z; z[0]=0.f; z[1]=0.f; z[2]=0.f; z[3]=0.f; return z; }

#define SWZ8(row,k) ((k) ^ (((row)&7)<<3))

// ---------------- prep: pack weights to f16 ----------------
__global__ void k_prep(const float* __restrict__ p_in, const float* __restrict__ g_in,
                       const float* __restrict__ g_out, const float* __restrict__ p_out,
                       u16* __restrict__ W1, u16* __restrict__ Wgo, u16* __restrict__ Wpo){
  int t = blockIdx.x*256 + threadIdx.x;
  if (t < 65536){
    int row = t >> 7, k = t & 127;
    int c = row >> 6, cc = row & 63, n = cc >> 4, col = cc & 15;
    int d = c*32 + (n>>1)*16 + col;
    W1[t] = f2h((n&1) ? g_in[d*128+k] : p_in[d*128+k]);
  } else if (t < 81920){
    int u = t - 65536; Wgo[u] = f2h(g_out[u]);
  } else if (t < 98304){
    int u = t - 81920; Wpo[u] = f2h(p_out[u]);
  }
}

// ---------------- S1: register-LN + in-projections + gate ----------------
// block = 128 rows.  a_t/b_t: [128 d][262144 r] f16. gate: [r][128 d] f16.
__global__ __launch_bounds__(256,4) void k_s1(
    const float* __restrict__ x, const float* __restrict__ mask,
    const float* __restrict__ nw, const float* __restrict__ nb,
    const u16* __restrict__ W1, const u16* __restrict__ Wgo,
    u16* __restrict__ a_t, u16* __restrict__ b_t, u16* __restrict__ gate)
{
  __shared__ u16 w_s[64*128];     // 16KB weight chunk (source pre-swizzled)
  __shared__ u16 st_s[128*68];    // 17KB staging: a/b uses first 8KB, gate uses all

  const int tid = threadIdx.x, lane = tid & 63, w = tid >> 6;
  const int col = lane & 15, hi = lane >> 4;
  const int r0 = blockIdx.x * 128;

  auto issueW = [&](int c){
    const u16* wsrc = (c < 8) ? (W1 + c*8192) : (Wgo + (c-8)*8192);
    #pragma unroll
    for (int i = 0; i < 4; ++i){
      int idx8 = i*256 + tid;
      int nr = idx8 >> 4, kb = (idx8 & 15)*8;
      const u16* gp = wsrc + nr*128 + SWZ8(nr, kb);
      u16* lp = w_s + (size_t)(i*256 + w*64)*8;
      __builtin_amdgcn_global_load_lds((const __attribute__((address_space(1))) unsigned*)gp,
                                       (__attribute__((address_space(3))) unsigned*)lp, 16, 0, 0);
    }
  };

  issueW(0);   // overlaps the register-LN phase

  // LayerNorm in registers, fragments built directly (no LDS round-trip).
  // Thread's rows: w*32+m*16+col; its k-slices: kk*32+hi*8.
  f16x8 af[2][4];
  float4 mkq[2];
  #pragma unroll
  for (int m = 0; m < 2; ++m){
    const float* xr = x + (size_t)(r0 + w*32 + m*16 + col)*128 + hi*8;
    float4 xv[8];
    #pragma unroll
    for (int kk = 0; kk < 4; ++kk){
      xv[kk*2]   = *(const float4*)(xr + kk*32);
      xv[kk*2+1] = *(const float4*)(xr + kk*32 + 4);
    }
    float s = 0.f, q = 0.f;
    #pragma unroll
    for (int i = 0; i < 8; ++i){
      float4 v = xv[i];
      s += (v.x+v.y)+(v.z+v.w);
      q = fmaf(v.x,v.x,q); q = fmaf(v.y,v.y,q); q = fmaf(v.z,v.z,q); q = fmaf(v.w,v.w,q);
    }
    // full row lives in the 4 hi-lanes with same col
    s += __shfl_xor(s,16); q += __shfl_xor(q,16);
    s += __shfl_xor(s,32); q += __shfl_xor(q,32);
    float mu = s * 0.0078125f;
    float rs = rsqrtf(fmaxf(q*0.0078125f - mu*mu, 0.f) + 1e-5f);
    #pragma unroll
    for (int kk = 0; kk < 4; ++kk){
      const float* nwp = nw + kk*32 + hi*8;
      const float* nbp = nb + kk*32 + hi*8;
      float4 na = *(const float4*)nwp, nA = *(const float4*)(nwp+4);
      float4 ba = *(const float4*)nbp, bA = *(const float4*)(nbp+4);
      float4 va = xv[kk*2], vb = xv[kk*2+1];
      uint4 pv;
      pv.x = pk2h((va.x-mu)*rs*na.x+ba.x, (va.y-mu)*rs*na.y+ba.y);
      pv.y = pk2h((va.z-mu)*rs*na.z+ba.z, (va.w-mu)*rs*na.w+ba.w);
      pv.z = pk2h((vb.x-mu)*rs*nA.x+bA.x, (vb.y-mu)*rs*nA.y+bA.y);
      pv.w = pk2h((vb.z-mu)*rs*nA.z+bA.z, (vb.w-mu)*rs*nA.w+bA.w);
      __builtin_memcpy(&af[m][kk], &pv, 16);
    }
    mkq[m] = *(const float4*)(mask + r0 + w*32 + m*16 + hi*4);
  }
  __syncthreads();   // W(0) drained (compiler vmcnt(0) before barrier)

  for (int c = 0; c < 10; ++c){
    f16x8 bf[4][4];
    #pragma unroll
    for (int n = 0; n < 4; ++n){
      #pragma unroll
      for (int kk = 0; kk < 4; ++kk){
        int nr = n*16 + col;
        bf[n][kk] = *(const f16x8*)(&w_s[nr*128 + SWZ8(nr, kk*32 + hi*8)]);
      }
    }
    __syncthreads();            // all waves done reading w_s
    if (c < 9) issueW(c+1);     // prefetch overlaps MFMA + epilogue

    f32x4 acc[2][4];
    #pragma unroll
    for (int m = 0; m < 2; ++m)
      #pragma unroll
      for (int n = 0; n < 4; ++n) acc[m][n] = zero4();
    #pragma unroll
    for (int kk = 0; kk < 4; ++kk)
      #pragma unroll
      for (int m = 0; m < 2; ++m)
        #pragma unroll
        for (int n = 0; n < 4; ++n)
          acc[m][n] = __builtin_amdgcn_mfma_f32_16x16x32_f16(af[m][kk], bf[n][kk], acc[m][n], 0, 0, 0);

    if (c < 8){
      // h = p * sigmoid(g) * mask; p in acc[m][2t], g in acc[m][2t+1] (same lane)
      u16* hbuf = st_s;
      #pragma unroll
      for (int m = 0; m < 2; ++m){
        #pragma unroll
        for (int t2 = 0; t2 < 2; ++t2){
          f32x4 pv = acc[m][2*t2], gv = acc[m][2*t2+1];
          int dl = t2*16 + col;
          int rb = w*32 + m*16 + hi*4;
          int ad = dl*128 + (rb ^ ((dl & 15) << 3));
          const float* mkp = (const float*)&mkq[m];
          float h0 = pv[0]*sigm(gv[0])*mkp[0];
          float h1 = pv[1]*sigm(gv[1])*mkp[1];
          float h2 = pv[2]*sigm(gv[2])*mkp[2];
          float h3 = pv[3]*sigm(gv[3])*mkp[3];
          uint2 uv; uv.x = pk2h(h0, h1); uv.y = pk2h(h2, h3);
          *(uint2*)(&hbuf[ad]) = uv;
        }
      }
      __syncthreads();          // staging visible; W(c+1) drained here
      {
        int dl = tid >> 3, seg = (tid & 7)*16;
        int dg = c*32 + dl;
        u16* dst = (dg < 128 ? a_t + (size_t)dg*262144 : b_t + (size_t)(dg-128)*262144) + r0;
        int sw = (dl & 15) << 3;
        uint4 v0 = *(const uint4*)(&hbuf[dl*128 + (seg ^ sw)]);
        uint4 v1 = *(const uint4*)(&hbuf[dl*128 + ((seg + 8) ^ sw)]);
        *(uint4*)(dst + seg)     = v0;
        *(uint4*)(dst + seg + 8) = v1;
      }
    } else {
      // gate chunk: gate = sigmoid(acc), row-major store
      #pragma unroll
      for (int m = 0; m < 2; ++m)
        #pragma unroll
        for (int n = 0; n < 4; ++n)
          #pragma unroll
          for (int j = 0; j < 4; ++j){
            int row = w*32 + m*16 + hi*4 + j;
            st_s[row*68 + n*16 + col] = f2h(sigm(acc[m][n][j]));
          }
      __syncthreads();
      {
        int row = tid >> 1, base = (tid & 1)*32;
        u16* dst = gate + (size_t)(r0+row)*128 + (c-8)*64 + base;
        #pragma unroll
        for (int i2 = 0; i2 < 4; ++i2)
          *(uint4*)(dst + i2*8) = *(const uint4*)(&st_s[row*68 + base + i2*8]);
      }
    }
  }
}

// ---------------- S2: 128 batched NT-GEMMs  t[d][i][j] = sum_k a[d][i][k] b[d][j][k] ----------------
__global__ __launch_bounds__(256,4) void k_s2(
    const u16* __restrict__ a_t, const u16* __restrict__ b_t, u16* __restrict__ t_dm)
{
  __shared__ u16 A_s[128*32];
  __shared__ u16 B_s[128*32];
  __shared__ u16 C_s[64*136];     // halved: staged in two 64-row rounds

  const int tid = threadIdx.x, lane = tid & 63, w = tid >> 6;
  const int col = lane & 15, hi = lane >> 4;

  // bijective XCD swizzle (nwg=2048, 8 XCDs): each XCD gets contiguous d-range
  int bid = blockIdx.x + (blockIdx.y << 4);
  int sw = (bid & 7)*256 + (bid >> 3);
  const int d = sw >> 4;
  const int tile = sw & 15;
  const int ti = (tile >> 2) * 128, tj = (tile & 3) * 128;
  const u16* Ab = a_t + (size_t)d * 262144;
  const u16* Bb = b_t + (size_t)d * 262144;
  const int wr = (w >> 1) * 64, wc = (w & 1) * 64;

  f32x4 acc[4][4];
  #pragma unroll
  for (int m=0;m<4;m++){
    #pragma unroll
    for (int n=0;n<4;n++) acc[m][n] = zero4();
  }

  const int srow = lane >> 2;
  const int scol = (lane & 3) * 8;

  for (int k0 = 0; k0 < 512; k0 += 32){
    __syncthreads();
    #pragma unroll
    for (int j = 0; j < 2; ++j){
      int chunk = w*2 + j;
      int row = chunk*16 + srow;
      int e = scol ^ ((((row >> 1) & 3)) << 3);
      const unsigned int* gpA = (const unsigned int*)(Ab + (size_t)(ti + row)*512 + k0 + e);
      unsigned int* lpA = (unsigned int*)(&A_s[chunk*512]);
      __builtin_amdgcn_global_load_lds((const __attribute__((address_space(1))) unsigned int*)gpA,
                                       (__attribute__((address_space(3))) unsigned int*)lpA, 16, 0, 0);
      const unsigned int* gpB = (const unsigned int*)(Bb + (size_t)(tj + row)*512 + k0 + e);
      unsigned int* lpB = (unsigned int*)(&B_s[chunk*512]);
      __builtin_amdgcn_global_load_lds((const __attribute__((address_space(1))) unsigned int*)gpB,
                                       (__attribute__((address_space(3))) unsigned int*)lpB, 16, 0, 0);
    }
    __syncthreads();

    f16x8 af[4], bfv[4];
    #pragma unroll
    for (int m=0;m<4;m++){
      int row = wr + m*16 + col;
      af[m] = *(const f16x8*)(&A_s[row*32 + (hi*8 ^ ((((row>>1)&3))<<3))]);
    }
    #pragma unroll
    for (int n=0;n<4;n++){
      int row = wc + n*16 + col;
      bfv[n] = *(const f16x8*)(&B_s[row*32 + (hi*8 ^ ((((row>>1)&3))<<3))]);
    }
    #pragma unroll
    for (int m=0;m<4;m++){
      #pragma unroll
      for (int n=0;n<4;n++)
        acc[m][n] = __builtin_amdgcn_mfma_f32_16x16x32_f16(af[m], bfv[n], acc[m][n], 0, 0, 0);
    }
  }

  // epilogue: two half-tiles through 17KB C_s
  u16* dst0 = t_dm + (size_t)d*262144 + (size_t)ti*512 + tj;
  #pragma unroll
  for (int h = 0; h < 2; ++h){
    if ((w >> 1) == h){
      #pragma unroll
      for (int m=0;m<4;m++){
        #pragma unroll
        for (int n=0;n<4;n++){
          #pragma unroll
          for (int j=0;j<4;j++){
            int row = m*16 + hi*4 + j, cl = wc + n*16 + col;
            C_s[row*136 + cl] = f2h(acc[m][n][j]);
          }
        }
      }
    }
    __syncthreads();
    #pragma unroll
    for (int s=0;s<4;s++){
      int gi = s*256 + tid;
      int row = gi >> 4, seg = (gi & 15) * 8;
      *(uint4*)(dst0 + (size_t)(h*64 + row)*512 + seg) = *(const uint4*)(&C_s[row*136 + seg]);
    }
    if (h == 0) __syncthreads();
  }
}

// ---------------- S3: LN(t) @ p_out^T * gate -> out (f32) ----------------
#define TS 136   // padded t_s row stride (16B aligned, 4-bank shift/row)
__global__ __launch_bounds__(256) void k_s3(
    const u16* __restrict__ t_dm, const u16* __restrict__ gate, const u16* __restrict__ Wpo,
    const float* __restrict__ nw, const float* __restrict__ nb,
    float* __restrict__ out)
{
  __shared__ u16 t_s[128*TS];    // [j][d], padded rows
  __shared__ u16 w_s[128*128];   // Wpo swizzled; reused as C staging

  const int tid = threadIdx.x, lane = tid & 63, w = tid >> 6;
  const int col = lane & 15, hi = lane >> 4;
  const int bi = blockIdx.x >> 2;
  const int jc = (blockIdx.x & 3) * 128;

  // phase A: Wpo load + t tile via in-register 8x8 u16 transpose
  {
    int dd = tid >> 1, jh = (tid & 1) * 64;
    const u16* wsrc = Wpo + (size_t)dd*128 + jh;
    #pragma unroll
    for (int s=0;s<8;s++){
      uint4 v = *(const uint4*)(wsrc + s*8);
      *(uint4*)(&w_s[dd*128 + SWZ8(dd, jh + s*8)]) = v;
    }
    int dblk = tid >> 4, jblk = tid & 15;       // 8x8 oct-tile per thread
    const u16* src = t_dm + (size_t)(dblk*8)*262144 + (size_t)bi*512 + jc + jblk*8;
    uint4 rv[8];
    #pragma unroll
    for (int r=0;r<8;r++) rv[r] = *(const uint4*)(src + (size_t)r*262144);
    const unsigned* pr = (const unsigned*)rv;
    #pragma unroll
    for (int j=0;j<8;j++){
      unsigned sel = (j&1) ? 0x07060302u : 0x05040100u;
      int dw = j >> 1;
      uint4 ov;
      ov.x = __builtin_amdgcn_perm(pr[4+dw],  pr[0+dw],  sel);
      ov.y = __builtin_amdgcn_perm(pr[12+dw], pr[8+dw],  sel);
      ov.z = __builtin_amdgcn_perm(pr[20+dw], pr[16+dw], sel);
      ov.w = __builtin_amdgcn_perm(pr[28+dw], pr[24+dw], sel);
      int row = jblk*8 + j;
      *(uint4*)(&t_s[row*TS + dblk*8]) = ov;
    }
  }
  __syncthreads();

  // phase B: LayerNorm over d for each j (2 threads per j)
  {
    int j = tid >> 1, dh = (tid & 1) * 64;
    float s = 0.f, q = 0.f;
    #pragma unroll
    for (int sc=0;sc<8;sc++){
      uint4 v = *(const uint4*)(&t_s[j*TS + dh + sc*8]);
      const u16* ev = (const u16*)&v;
      #pragma unroll
      for (int u=0;u<8;u++){ float f = h2f(ev[u]); s += f; q = fmaf(f,f,q); }
    }
    s += __shfl_xor(s, 1); q += __shfl_xor(q, 1);
    float mu = s * 0.0078125f;
    float rs = rsqrtf(fmaxf(q*0.0078125f - mu*mu, 0.f) + 1e-5f);
    #pragma unroll
    for (int sc=0;sc<8;sc++){
      int db = dh + sc*8;
      u16* p = &t_s[j*TS + db];
      uint4 v = *(uint4*)p;
      u16* ev = (u16*)&v;
      float4 w0 = *(const float4*)(nw + db);
      float4 w1 = *(const float4*)(nw + db + 4);
      float4 b0 = *(const float4*)(nb + db);
      float4 b1 = *(const float4*)(nb + db + 4);
      float wv[8] = {w0.x,w0.y,w0.z,w0.w,w1.x,w1.y,w1.z,w1.w};
      float bv[8] = {b0.x,b0.y,b0.z,b0.w,b1.x,b1.y,b1.z,b1.w};
      #pragma unroll
      for (int u=0;u<8;u++){
        float f = (h2f(ev[u]) - mu)*rs*wv[u] + bv[u];
        ev[u] = f2h(f);
      }
      *(uint4*)p = v;
    }
  }
  __syncthreads();

  // phase C: GEMM [128 j][128 d] @ Wpo^T
  f32x4 acc[2][8];
  #pragma unroll
  for (int m=0;m<2;m++){
    #pragma unroll
    for (int n=0;n<8;n++) acc[m][n] = zero4();
  }
  #pragma unroll
  for (int kk=0;kk<4;kk++){
    f16x8 af[2];
    #pragma unroll
    for (int m=0;m<2;m++){
      int row = w*32 + m*16 + col;
      af[m] = *(const f16x8*)(&t_s[row*TS + kk*32 + hi*8]);
    }
    #pragma unroll
    for (int n=0;n<8;n++){
      int rw = n*16 + col;
      f16x8 bv = *(const f16x8*)(&w_s[rw*128 + SWZ8(rw, kk*32 + hi*8)]);
      #pragma unroll
      for (int m=0;m<2;m++)
        acc[m][n] = __builtin_amdgcn_mfma_f32_16x16x32_f16(af[m], bv, acc[m][n], 0, 0, 0);
    }
  }
  __syncthreads();

  // phase D: stage C (f16) into w_s, then gated f32 write
  #pragma unroll
  for (int m=0;m<2;m++){
    #pragma unroll
    for (int n=0;n<8;n++){
      #pragma unroll
      for (int j=0;j<4;j++){
        int row = w*32 + m*16 + hi*4 + j, cl = n*16 + col;
        w_s[row*128 + SWZ8(row, cl)] = f2h(acc[m][n][j]);
      }
    }
  }
  __syncthreads();
  {
    int j = tid >> 1, dh = (tid & 1) * 64;
    size_t r = (size_t)bi*512 + jc + j;
    const u16* g = gate + r*128;
    float* o = out + r*128;
    #pragma unroll
    for (int sc=0;sc<8;sc++){
      int n8 = dh + sc*8;
      uint4 cv = *(const uint4*)(&w_s[j*128 + SWZ8(j, n8)]);
      uint4 gv = *(const uint4*)(g + n8);
      const u16* ce = (const u16*)&cv;
      const u16* ge = (const u16*)&gv;
      float4 o0, o1;
      o0.x = h2f(ce[0])*h2f(ge[0]);
      o0.y = h2f(ce[1])*h2f(ge[1]);
      o0.z = h2f(ce[2])*h2f(ge[2]);
      o0.w = h2f(ce[3])*h2f(ge[3]);
      o1.x = h2f(ce[4])*h2f(ge[4]);
      o1.y = h2f(ce[5])*h2f(ge[5]);
      o1.z = h2f(ce[6])*h2f(ge[6]);
      o1.w = h2f(ce[7])*h2f(ge[7]);
      *(float4*)(o + n8)     = o0;
      *(float4*)(o + n8 + 4) = o1;
    }
  }
}

extern "C" void kernel_launch(void* const* d_in, const int* in_sizes, int n_in,
                              void* d_out, int out_size, void* d_ws, size_t ws_size,
                              hipStream_t stream){
  const float* x    = (const float*)d_in[0];
  const float* mask = (const float*)d_in[1];
  const float* niw  = (const float*)d_in[2];
  const float* nib  = (const float*)d_in[3];
  const float* piw  = (const float*)d_in[4];
  const float* giw  = (const float*)d_in[5];
  const float* now  = (const float*)d_in[6];
  const float* nob  = (const float*)d_in[7];
  const float* pow_ = (const float*)d_in[8];
  const float* gow  = (const float*)d_in[9];
  float* out = (float*)d_out;

  char* ws = (char*)d_ws;
  u16* a_t  = (u16*)(ws);                          // 64 MB  [128][262144]
  u16* b_t  = (u16*)(ws + (size_t)67108864);       // 64 MB
  u16* t_dm = (u16*)(ws + (size_t)134217728);      // 64 MB  [128][512][512]
  u16* gate = (u16*)(ws + (size_t)201326592);      // 64 MB  [262144][128]
  u16* W1   = (u16*)(ws + (size_t)268435456);      // 128 KB
  u16* Wgo  = W1 + 65536;                          // 32 KB
  u16* Wpo  = Wgo + 16384;                         // 32 KB

  k_prep<<<384, 256, 0, stream>>>(piw, giw, gow, pow_, W1, Wgo, Wpo);
  k_s1<<<2048, 256, 0, stream>>>(x, mask, niw, nib, W1, Wgo, a_t, b_t, gate);
  k_s2<<<dim3(16,128), 256, 0, stream>>>(a_t, b_t, t_dm);
  k_s3<<<2048, 256, 0, stream>>>(t_dm, gate, Wpo, now, nob, out);
}

// Round 7
// 304.472 us; speedup vs baseline: 1.0622x; 1.0622x over previous
//
#include <hip/hip_runtime.h>

typedef unsigned short u16;
typedef _Float16 f16x8 __attribute__((ext_vector_type(8)));
typedef float f32x4 __attribute__((ext_vector_type(4)));

__device__ __forceinline__ u16 f2h(float f){
  _Float16 h = (_Float16)f; u16 u; __builtin_memcpy(&u, &h, 2); return u;
}
__device__ __forceinline__ float h2f(u16 u){
  _Float16 h; __builtin_memcpy(&h, &u, 2); return (float)h;
}
__device__ __forceinline__ unsigned pk2h(float a, float b){
  auto r = __builtin_amdgcn_cvt_pkrtz(a, b);   // __fp16 ext_vector_type(2)
  unsigned u; __builtin_memcpy(&u, &r, 4); return u;
}
__device__ __forceinline__ float sigm(float x){ return 1.0f/(1.0f + __expf(-x)); }
__device__ __forceinline__ f32x4 zero4(){ f32x4 z; z[0]=0.f; z[1]=0.f; z[2]=0.f; z[3]=0.f; return z; }

#define SWZ8(row,k) ((k) ^ (((row)&7)<<3))

// ---------------- prep: pack weights to f16 ----------------
// W1[512][128]: MFMA-col cc of chunk c -> row c*64+cc; d = c*32 + (n>>1)*16 + col,
// row holds (n&1 ? g_in : p_in)[d][:]  -> p and g for dim d land in the SAME lane.
__global__ void k_prep(const float* __restrict__ p_in, const float* __restrict__ g_in,
                       const float* __restrict__ g_out, const float* __restrict__ p_out,
                       u16* __restrict__ W1, u16* __restrict__ Wgo, u16* __restrict__ Wpo){
  int t = blockIdx.x*256 + threadIdx.x;
  if (t < 65536){
    int row = t >> 7, k = t & 127;
    int c = row >> 6, cc = row & 63, n = cc >> 4, col = cc & 15;
    int d = c*32 + (n>>1)*16 + col;
    W1[t] = f2h((n&1) ? g_in[d*128+k] : p_in[d*128+k]);
  } else if (t < 81920){
    int u = t - 65536; Wgo[u] = f2h(g_out[u]);
  } else if (t < 98304){
    int u = t - 81920; Wpo[u] = f2h(p_out[u]);
  }
}

// ---------------- S1: LN + paired in-projection, a/b transposed store + x_in store ----------------
// block = 128 rows.  a_t/b_t: [128 d][262144 r] f16.  x16: [262144 r][128 k] f16.
__global__ __launch_bounds__(256,3) void k_s1(
    const float* __restrict__ x, const float* __restrict__ mask,
    const float* __restrict__ nw, const float* __restrict__ nb,
    const u16* __restrict__ W1,
    u16* __restrict__ a_t, u16* __restrict__ b_t, u16* __restrict__ x16)
{
  __shared__ u16 xh_s[128*128];   // 32KB: x_in f16 (swizzled rows); rows 0..31 reused as staging
  __shared__ u16 w_s[64*128];     // 16KB: weight chunk (source pre-swizzled)
  __shared__ float mask_s[128];

  const int tid = threadIdx.x, lane = tid & 63, w = tid >> 6;
  const int col = lane & 15, hi = lane >> 4;
  const int r0 = blockIdx.x * 128;

  auto issueW = [&](int c){
    const u16* wsrc = W1 + c*8192;
    #pragma unroll
    for (int i = 0; i < 4; ++i){
      int idx8 = i*256 + tid;
      int nr = idx8 >> 4, kb = (idx8 & 15)*8;
      const u16* gp = wsrc + nr*128 + SWZ8(nr, kb);
      u16* lp = w_s + (size_t)(i*256 + w*64)*8;
      __builtin_amdgcn_global_load_lds((const __attribute__((address_space(1))) unsigned*)gp,
                                       (__attribute__((address_space(3))) unsigned*)lp, 16, 0, 0);
    }
  };

  if (tid < 128) mask_s[tid] = mask[r0 + tid];
  issueW(0);   // overlaps LN phase

  // phase 1: LayerNorm — 4 rows/wave in parallel (16 lanes/row, 8 f32/lane, coalesced)
  {
    const int g = lane >> 4, cl = lane & 15;
    float4 nwa = *(const float4*)(nw + cl*8);
    float4 nwb = *(const float4*)(nw + cl*8 + 4);
    float4 nba = *(const float4*)(nb + cl*8);
    float4 nbb = *(const float4*)(nb + cl*8 + 4);
    #pragma unroll
    for (int it = 0; it < 8; ++it){
      int row = w*32 + it*4 + g;
      const float* xr = x + (size_t)(r0+row)*128 + cl*8;
      float4 xa = *(const float4*)xr;
      float4 xb = *(const float4*)(xr + 4);
      float s = ((xa.x+xa.y)+(xa.z+xa.w)) + ((xb.x+xb.y)+(xb.z+xb.w));
      float q = xa.x*xa.x; q = fmaf(xa.y,xa.y,q); q = fmaf(xa.z,xa.z,q); q = fmaf(xa.w,xa.w,q);
      q = fmaf(xb.x,xb.x,q); q = fmaf(xb.y,xb.y,q); q = fmaf(xb.z,xb.z,q); q = fmaf(xb.w,xb.w,q);
      #pragma unroll
      for (int off = 1; off < 16; off <<= 1){ s += __shfl_xor(s, off); q += __shfl_xor(q, off); }
      float mu = s * 0.0078125f;
      float rs = rsqrtf(fmaxf(q*0.0078125f - mu*mu, 0.f) + 1e-5f);
      uint4 pv;
      pv.x = pk2h((xa.x-mu)*rs*nwa.x+nba.x, (xa.y-mu)*rs*nwa.y+nba.y);
      pv.y = pk2h((xa.z-mu)*rs*nwa.z+nba.z, (xa.w-mu)*rs*nwa.w+nba.w);
      pv.z = pk2h((xb.x-mu)*rs*nwb.x+nbb.x, (xb.y-mu)*rs*nwb.y+nbb.y);
      pv.w = pk2h((xb.z-mu)*rs*nwb.z+nbb.z, (xb.w-mu)*rs*nwb.w+nbb.w);
      *(uint4*)(&xh_s[row*128 + SWZ8(row, cl*8)]) = pv;
    }
  }
  __syncthreads();   // x_in visible; W(0) drained

  // A-fragments register-cached once
  f16x8 af[2][4];
  #pragma unroll
  for (int m = 0; m < 2; ++m){
    #pragma unroll
    for (int kk = 0; kk < 4; ++kk){
      int row = w*32 + m*16 + col;
      af[m][kk] = *(const f16x8*)(&xh_s[row*128 + SWZ8(row, kk*32 + hi*8)]);
    }
  }
  float mk[2][4];
  #pragma unroll
  for (int m = 0; m < 2; ++m)
    #pragma unroll
    for (int j = 0; j < 4; ++j) mk[m][j] = mask_s[w*32 + m*16 + hi*4 + j];

  // x_in -> global (coalesced, unswizzle): 2 threads/row x 8 uint4 = 128 elems/row
  {
    int row = tid >> 1, half = (tid & 1)*64;
    u16* dst = x16 + (size_t)(r0+row)*128 + half;
    int sw = (row & 7) << 3;
    #pragma unroll
    for (int s = 0; s < 8; ++s){
      uint4 v = *(const uint4*)(&xh_s[row*128 + ((half + s*8) ^ sw)]);
      *(uint4*)(dst + s*8) = v;
    }
  }

  for (int c = 0; c < 8; ++c){
    f16x8 bf[4][4];
    #pragma unroll
    for (int n = 0; n < 4; ++n){
      #pragma unroll
      for (int kk = 0; kk < 4; ++kk){
        int nr = n*16 + col;
        bf[n][kk] = *(const f16x8*)(&w_s[nr*128 + SWZ8(nr, kk*32 + hi*8)]);
      }
    }
    __syncthreads();            // all waves done reading w_s (and xh_s reads done)
    if (c < 7) issueW(c+1);     // prefetch overlaps MFMA + epilogue

    f32x4 acc[2][4];
    #pragma unroll
    for (int m = 0; m < 2; ++m)
      #pragma unroll
      for (int n = 0; n < 4; ++n) acc[m][n] = zero4();
    #pragma unroll
    for (int kk = 0; kk < 4; ++kk)
      #pragma unroll
      for (int m = 0; m < 2; ++m)
        #pragma unroll
        for (int n = 0; n < 4; ++n)
          acc[m][n] = __builtin_amdgcn_mfma_f32_16x16x32_f16(af[m][kk], bf[n][kk], acc[m][n], 0, 0, 0);

    // h = p * sigmoid(g) * mask; p in acc[m][2t], g in acc[m][2t+1] (same lane)
    u16* hbuf = xh_s;
    #pragma unroll
    for (int m = 0; m < 2; ++m){
      #pragma unroll
      for (int t2 = 0; t2 < 2; ++t2){
        f32x4 pv = acc[m][2*t2], gv = acc[m][2*t2+1];
        int dl = t2*16 + col;
        int rb = w*32 + m*16 + hi*4;
        int ad = dl*128 + (rb ^ ((dl & 15) << 3));
        float h0 = pv[0]*sigm(gv[0])*mk[m][0];
        float h1 = pv[1]*sigm(gv[1])*mk[m][1];
        float h2 = pv[2]*sigm(gv[2])*mk[m][2];
        float h3 = pv[3]*sigm(gv[3])*mk[m][3];
        uint2 uv; uv.x = pk2h(h0, h1); uv.y = pk2h(h2, h3);
        *(uint2*)(&hbuf[ad]) = uv;
      }
    }
    __syncthreads();            // staging visible; W(c+1) drained here
    {
      int dl = tid >> 3, seg = (tid & 7)*16;
      int dg = c*32 + dl;
      u16* dst = (dg < 128 ? a_t + (size_t)dg*262144 : b_t + (size_t)(dg-128)*262144) + r0;
      int sw = (dl & 15) << 3;
      uint4 v0 = *(const uint4*)(&hbuf[dl*128 + (seg ^ sw)]);
      uint4 v1 = *(const uint4*)(&hbuf[dl*128 + ((seg + 8) ^ sw)]);
      *(uint4*)(dst + seg)     = v0;
      *(uint4*)(dst + seg + 8) = v1;
    }
  }
}

// ---------------- S2: 128 batched NT-GEMMs, dbuf pipeline ----------------
__global__ __launch_bounds__(256,4) void k_s2(
    const u16* __restrict__ a_t, const u16* __restrict__ b_t, u16* __restrict__ t_dm)
{
  __shared__ u16 AB_s[2][2][4096];   // 32KB: [buf][A/B][128row x 32k]; C staging aliases

  const int tid = threadIdx.x, lane = tid & 63, w = tid >> 6;
  const int col = lane & 15, hi = lane >> 4;

  // bijective XCD swizzle (nwg=2048): each XCD gets a contiguous d-range
  int bid = blockIdx.x + (blockIdx.y << 4);
  int sw = (bid & 7)*256 + (bid >> 3);
  const int d = sw >> 4;
  const int tile = sw & 15;
  const int ti = (tile >> 2) * 128, tj = (tile & 3) * 128;
  const u16* Ab = a_t + (size_t)d * 262144;
  const u16* Bb = b_t + (size_t)d * 262144;
  const int wr = (w >> 1) * 64, wc = (w & 1) * 64;

  f32x4 acc[4][4];
  #pragma unroll
  for (int m=0;m<4;m++){
    #pragma unroll
    for (int n=0;n<4;n++) acc[m][n] = zero4();
  }

  const int srow = lane >> 2;
  const int scol = (lane & 3) * 8;

  auto STAGE = [&](int buf, int k0){
    #pragma unroll
    for (int j = 0; j < 2; ++j){
      int chunk = w*2 + j;
      int row = chunk*16 + srow;
      int e = scol ^ ((((row >> 1) & 3)) << 3);
      const unsigned int* gpA = (const unsigned int*)(Ab + (size_t)(ti + row)*512 + k0 + e);
      unsigned int* lpA = (unsigned int*)(&AB_s[buf][0][chunk*512]);
      __builtin_amdgcn_global_load_lds((const __attribute__((address_space(1))) unsigned int*)gpA,
                                       (__attribute__((address_space(3))) unsigned int*)lpA, 16, 0, 0);
      const unsigned int* gpB = (const unsigned int*)(Bb + (size_t)(tj + row)*512 + k0 + e);
      unsigned int* lpB = (unsigned int*)(&AB_s[buf][1][chunk*512]);
      __builtin_amdgcn_global_load_lds((const __attribute__((address_space(1))) unsigned int*)gpB,
                                       (__attribute__((address_space(3))) unsigned int*)lpB, 16, 0, 0);
    }
  };

  STAGE(0, 0);
  int cur = 0;
  for (int k0 = 0; k0 < 512; k0 += 32){
    __syncthreads();                 // stage(cur) complete (vmcnt drained at barrier)
    if (k0 + 32 < 512) STAGE(cur ^ 1, k0 + 32);   // overlaps MFMA below
    f16x8 af[4], bfv[4];
    #pragma unroll
    for (int m=0;m<4;m++){
      int row = wr + m*16 + col;
      af[m] = *(const f16x8*)(&AB_s[cur][0][row*32 + (hi*8 ^ ((((row>>1)&3))<<3))]);
    }
    #pragma unroll
    for (int n=0;n<4;n++){
      int row = wc + n*16 + col;
      bfv[n] = *(const f16x8*)(&AB_s[cur][1][row*32 + (hi*8 ^ ((((row>>1)&3))<<3))]);
    }
    #pragma unroll
    for (int m=0;m<4;m++){
      #pragma unroll
      for (int n=0;n<4;n++)
        acc[m][n] = __builtin_amdgcn_mfma_f32_16x16x32_f16(af[m], bfv[n], acc[m][n], 0, 0, 0);
    }
    cur ^= 1;
  }

  // epilogue: two half-tiles through aliased C staging (A/B buffers dead)
  u16* C_s = &AB_s[0][0][0];   // 64*136 u16 = 17KB <= 32KB
  __syncthreads();
  u16* dst0 = t_dm + (size_t)d*262144 + (size_t)ti*512 + tj;
  #pragma unroll
  for (int h = 0; h < 2; ++h){
    if ((w >> 1) == h){
      #pragma unroll
      for (int m=0;m<4;m++){
        #pragma unroll
        for (int n=0;n<4;n++){
          #pragma unroll
          for (int j=0;j<4;j++){
            int row = m*16 + hi*4 + j, cl = wc + n*16 + col;
            C_s[row*136 + cl] = f2h(acc[m][n][j]);
          }
        }
      }
    }
    __syncthreads();
    #pragma unroll
    for (int s=0;s<4;s++){
      int gi = s*256 + tid;
      int row = gi >> 4, seg = (gi & 15) * 8;
      *(uint4*)(dst0 + (size_t)(h*64 + row)*512 + seg) = *(const uint4*)(&C_s[row*136 + seg]);
    }
    if (h == 0) __syncthreads();
  }
}

// ---------------- S3: gate GEMM + LN(t) @ p_out^T * gate -> out (f32) ----------------
#define TS 136
__global__ __launch_bounds__(256,2) void k_s3(
    const u16* __restrict__ t_dm, const u16* __restrict__ x16,
    const u16* __restrict__ Wgo, const u16* __restrict__ Wpo,
    const float* __restrict__ nw, const float* __restrict__ nb,
    float* __restrict__ out)
{
  __shared__ u16 t_s[128*TS];    // x_in tile (stride 128, swz), then t tile (stride TS)
  __shared__ u16 w_s[128*128];   // Wgo, then Wpo, then product staging

  const int tid = threadIdx.x, lane = tid & 63, w = tid >> 6;
  const int col = lane & 15, hi = lane >> 4;
  const int bi = blockIdx.x >> 2;
  const int jc = (blockIdx.x & 3) * 128;
  const size_t rbase = (size_t)bi*512 + jc;

  // phase A1: Wgo -> w_s (swz), x_in rows -> t_s (stride 128, swz)
  {
    int dd = tid >> 1, jh = (tid & 1) * 64;
    const u16* wsrc = Wgo + (size_t)dd*128 + jh;
    const u16* xsrc = x16 + (rbase + dd)*128 + jh;
    #pragma unroll
    for (int s=0;s<8;s++){
      uint4 v = *(const uint4*)(wsrc + s*8);
      *(uint4*)(&w_s[dd*128 + SWZ8(dd, jh + s*8)]) = v;
      uint4 xv = *(const uint4*)(xsrc + s*8);
      *(uint4*)(&t_s[dd*128 + SWZ8(dd, jh + s*8)]) = xv;
    }
  }
  __syncthreads();

  // phase B1: gate = sigmoid(x_in @ Wgo^T), kept packed f16 in registers
  unsigned gt[2][8][2];
  {
    f32x4 gacc[2][8];
    #pragma unroll
    for (int m=0;m<2;m++)
      #pragma unroll
      for (int n=0;n<8;n++) gacc[m][n] = zero4();
    #pragma unroll
    for (int kk=0;kk<4;kk++){
      f16x8 af[2];
      #pragma unroll
      for (int m=0;m<2;m++){
        int row = w*32 + m*16 + col;
        af[m] = *(const f16x8*)(&t_s[row*128 + SWZ8(row, kk*32 + hi*8)]);
      }
      #pragma unroll
      for (int n=0;n<8;n++){
        int rw = n*16 + col;
        f16x8 bv = *(const f16x8*)(&w_s[rw*128 + SWZ8(rw, kk*32 + hi*8)]);
        #pragma unroll
        for (int m=0;m<2;m++)
          gacc[m][n] = __builtin_amdgcn_mfma_f32_16x16x32_f16(af[m], bv, gacc[m][n], 0, 0, 0);
      }
    }
    #pragma unroll
    for (int m=0;m<2;m++)
      #pragma unroll
      for (int n=0;n<8;n++){
        gt[m][n][0] = pk2h(sigm(gacc[m][n][0]), sigm(gacc[m][n][1]));
        gt[m][n][1] = pk2h(sigm(gacc[m][n][2]), sigm(gacc[m][n][3]));
      }
  }
  __syncthreads();

  // phase A2: t tile via in-register 8x8 u16 transpose -> t_s (stride TS); Wpo -> w_s
  {
    int dd = tid >> 1, jh = (tid & 1) * 64;
    const u16* wsrc = Wpo + (size_t)dd*128 + jh;
    #pragma unroll
    for (int s=0;s<8;s++){
      uint4 v = *(const uint4*)(wsrc + s*8);
      *(uint4*)(&w_s[dd*128 + SWZ8(dd, jh + s*8)]) = v;
    }
    int dblk = tid >> 4, jblk = tid & 15;
    const u16* src = t_dm + (size_t)(dblk*8)*262144 + rbase + jblk*8;
    uint4 rv[8];
    #pragma unroll
    for (int r=0;r<8;r++) rv[r] = *(const uint4*)(src + (size_t)r*262144);
    const unsigned* pr = (const unsigned*)rv;
    #pragma unroll
    for (int j=0;j<8;j++){
      unsigned sel = (j&1) ? 0x07060302u : 0x05040100u;
      int dw = j >> 1;
      uint4 ov;
      ov.x = __builtin_amdgcn_perm(pr[4+dw],  pr[0+dw],  sel);
      ov.y = __builtin_amdgcn_perm(pr[12+dw], pr[8+dw],  sel);
      ov.z = __builtin_amdgcn_perm(pr[20+dw], pr[16+dw], sel);
      ov.w = __builtin_amdgcn_perm(pr[28+dw], pr[24+dw], sel);
      int row = jblk*8 + j;
      *(uint4*)(&t_s[row*TS + dblk*8]) = ov;
    }
  }
  __syncthreads();

  // phase B2: LayerNorm over d for each j (2 threads per j)
  {
    int j = tid >> 1, dh = (tid & 1) * 64;
    float s = 0.f, q = 0.f;
    #pragma unroll
    for (int sc=0;sc<8;sc++){
      uint4 v = *(const uint4*)(&t_s[j*TS + dh + sc*8]);
      const u16* ev = (const u16*)&v;
      #pragma unroll
      for (int u=0;u<8;u++){ float f = h2f(ev[u]); s += f; q = fmaf(f,f,q); }
    }
    s += __shfl_xor(s, 1); q += __shfl_xor(q, 1);
    float mu = s * 0.0078125f;
    float rs = rsqrtf(fmaxf(q*0.0078125f - mu*mu, 0.f) + 1e-5f);
    #pragma unroll
    for (int sc=0;sc<8;sc++){
      int db = dh + sc*8;
      u16* p = &t_s[j*TS + db];
      uint4 v = *(uint4*)p;
      u16* ev = (u16*)&v;
      float4 w0 = *(const float4*)(nw + db);
      float4 w1 = *(const float4*)(nw + db + 4);
      float4 b0 = *(const float4*)(nb + db);
      float4 b1 = *(const float4*)(nb + db + 4);
      float wv[8] = {w0.x,w0.y,w0.z,w0.w,w1.x,w1.y,w1.z,w1.w};
      float bv[8] = {b0.x,b0.y,b0.z,b0.w,b1.x,b1.y,b1.z,b1.w};
      #pragma unroll
      for (int u=0;u<8;u++){
        float f = (h2f(ev[u]) - mu)*rs*wv[u] + bv[u];
        ev[u] = f2h(f);
      }
      *(uint4*)p = v;
    }
  }
  __syncthreads();

  // phase C: GEMM [128 j][128 d] @ Wpo^T
  f32x4 acc[2][8];
  #pragma unroll
  for (int m=0;m<2;m++){
    #pragma unroll
    for (int n=0;n<8;n++) acc[m][n] = zero4();
  }
  #pragma unroll
  for (int kk=0;kk<4;kk++){
    f16x8 af[2];
    #pragma unroll
    for (int m=0;m<2;m++){
      int row = w*32 + m*16 + col;
      af[m] = *(const f16x8*)(&t_s[row*TS + kk*32 + hi*8]);
    }
    #pragma unroll
    for (int n=0;n<8;n++){
      int rw = n*16 + col;
      f16x8 bv = *(const f16x8*)(&w_s[rw*128 + SWZ8(rw, kk*32 + hi*8)]);
      #pragma unroll
      for (int m=0;m<2;m++)
        acc[m][n] = __builtin_amdgcn_mfma_f32_16x16x32_f16(af[m], bv, acc[m][n], 0, 0, 0);
    }
  }
  __syncthreads();

  // phase D: stage gated product (f16) into w_s, then coalesced f32 write
  #pragma unroll
  for (int m=0;m<2;m++){
    #pragma unroll
    for (int n=0;n<8;n++){
      #pragma unroll
      for (int j=0;j<4;j++){
        int row = w*32 + m*16 + hi*4 + j, cl = n*16 + col;
        float g = h2f((u16)(gt[m][n][j>>1] >> ((j&1)*16)));
        w_s[row*128 + SWZ8(row, cl)] = f2h(acc[m][n][j] * g);
      }
    }
  }
  __syncthreads();
  {
    int j = tid >> 1, dh = (tid & 1) * 64;
    float* o = out + (rbase + j)*128;
    #pragma unroll
    for (int sc=0;sc<8;sc++){
      int n8 = dh + sc*8;
      uint4 cv = *(const uint4*)(&w_s[j*128 + SWZ8(j, n8)]);
      const u16* ce = (const u16*)&cv;
      float4 o0, o1;
      o0.x = h2f(ce[0]); o0.y = h2f(ce[1]); o0.z = h2f(ce[2]); o0.w = h2f(ce[3]);
      o1.x = h2f(ce[4]); o1.y = h2f(ce[5]); o1.z = h2f(ce[6]); o1.w = h2f(ce[7]);
      *(float4*)(o + n8)     = o0;
      *(float4*)(o + n8 + 4) = o1;
    }
  }
}

extern "C" void kernel_launch(void* const* d_in, const int* in_sizes, int n_in,
                              void* d_out, int out_size, void* d_ws, size_t ws_size,
                              hipStream_t stream){
  const float* x    = (const float*)d_in[0];
  const float* mask = (const float*)d_in[1];
  const float* niw  = (const float*)d_in[2];
  const float* nib  = (const float*)d_in[3];
  const float* piw  = (const float*)d_in[4];
  const float* giw  = (const float*)d_in[5];
  const float* now  = (const float*)d_in[6];
  const float* nob  = (const float*)d_in[7];
  const float* pow_ = (const float*)d_in[8];
  const float* gow  = (const float*)d_in[9];
  float* out = (float*)d_out;

  char* ws = (char*)d_ws;
  u16* a_t  = (u16*)(ws);                          // 64 MB  [128][262144]
  u16* b_t  = (u16*)(ws + (size_t)67108864);       // 64 MB
  u16* t_dm = (u16*)(ws + (size_t)134217728);      // 64 MB  [128][512][512]
  u16* x16  = (u16*)(ws + (size_t)201326592);      // 64 MB  [262144][128]
  u16* W1   = (u16*)(ws + (size_t)268435456);      // 128 KB
  u16* Wgo  = W1 + 65536;                          // 32 KB
  u16* Wpo  = Wgo + 16384;                         // 32 KB

  k_prep<<<384, 256, 0, stream>>>(piw, giw, gow, pow_, W1, Wgo, Wpo);
  k_s1<<<2048, 256, 0, stream>>>(x, mask, niw, nib, W1, a_t, b_t, x16);
  k_s2<<<dim3(16,128), 256, 0, stream>>>(a_t, b_t, t_dm);
  k_s3<<<2048, 256, 0, stream>>>(t_dm, x16, Wgo, Wpo, now, nob, out);
}